// Round 3
// baseline (650.547 us; speedup 1.0000x reference)
//
#include <hip/hip_runtime.h>
#include <hip/hip_fp16.h>
#include <math.h>

#define HW 65536        // 256*256
#define XS_STRIDE 272   // 8 left pad + 256 + 8 right pad
#define XS_PLANE (256 * XS_STRIDE)

typedef float f4u __attribute__((ext_vector_type(4), aligned(4)));

// ---------------- K1: in_conv 1x1, 64 -> 16, write x as fp16 ----------------
__global__ __launch_bounds__(256) void k_inconv(const float* __restrict__ cen,
                                                const float* __restrict__ w,
                                                const float* __restrict__ bias,
                                                __half* __restrict__ xh) {
    __shared__ float sw[1024];
    __shared__ float sb[16];
    int tid = threadIdx.x;
    for (int i = tid; i < 1024; i += 256) sw[i] = w[i];
    if (tid < 16) sb[tid] = bias[tid];
    __syncthreads();

    long t  = (long)blockIdx.x * 256 + tid;   // quad index
    long p0 = t * 4;
    int  b  = (int)(p0 >> 16);
    int  hw = (int)(p0 & 65535);

    const float4* src = (const float4*)(cen + ((long)b * 64) * HW + hw);
    float4 acc[16];
#pragma unroll
    for (int o = 0; o < 16; o++) { float bv = sb[o]; acc[o] = make_float4(bv, bv, bv, bv); }

    for (int i = 0; i < 64; i++) {
        float4 v = src[(long)i * (HW / 4)];
#pragma unroll
        for (int o = 0; o < 16; o++) {
            float wv = sw[o * 64 + i];
            acc[o].x = fmaf(v.x, wv, acc[o].x);
            acc[o].y = fmaf(v.y, wv, acc[o].y);
            acc[o].z = fmaf(v.z, wv, acc[o].z);
            acc[o].w = fmaf(v.w, wv, acc[o].w);
        }
    }
#pragma unroll
    for (int o = 0; o < 16; o++) {
        __half2 lo = __floats2half2_rn(acc[o].x, acc[o].y);
        __half2 hi = __floats2half2_rn(acc[o].z, acc[o].w);
        __half2* dst = (__half2*)(xh + ((long)(b * 16 + o)) * HW + hw);
        dst[0] = lo;
        dst[1] = hi;
    }
}

// ---------------- K2: depthwise convs 1/3/5/7, write padded xs planes -------
__global__ __launch_bounds__(256) void k_dw(
    const __half* __restrict__ xh,
    const float* __restrict__ dw_w1, const float* __restrict__ dw_b1,
    const float* __restrict__ dw_w3, const float* __restrict__ dw_b3,
    const float* __restrict__ dw_w5, const float* __restrict__ dw_b5,
    const float* __restrict__ dw_w7, const float* __restrict__ dw_b7,
    float* __restrict__ xs, int cb) {

    const int pl  = blockIdx.y;          // local plane: bl*16 + c
    const int c   = pl & 15;
    const int bl  = pl >> 4;             // 0..1
    const int b   = cb * 2 + bl;
    const int ty0 = (blockIdx.x >> 3) * 32;
    const int tx0 = (blockIdx.x & 7) * 32;
    const int tid = threadIdx.x;

    __shared__ float lx[38 * 40];        // tile + halo 3, stride 40 (16B aligned rows)

    const __half* xp = xh + (long)(b * 16 + c) * HW;
    for (int i = tid; i < 38 * 38; i += 256) {
        int r  = i / 38;
        int cc = i - r * 38;
        int gy = ty0 - 3 + r, gx = tx0 - 3 + cc;
        float v = 0.f;
        if ((unsigned)gy < 256u && (unsigned)gx < 256u) v = __half2float(xp[gy * 256 + gx]);
        lx[r * 40 + cc] = v;
    }
    __syncthreads();

    const float* W7 = dw_w7 + c * 49;
    const float* W5 = dw_w5 + c * 25;
    const float* W3 = dw_w3 + c * 9;
    const float  W1 = dw_w1[c];
    const float  B1 = dw_b1[c], B3 = dw_b3[c], B5 = dw_b5[c], B7 = dw_b7[c];

    const int ty  = tid >> 3;            // 0..31
    const int tx4 = (tid & 7) * 4;       // 0,4,...,28

    float a7[4] = {0, 0, 0, 0}, a5[4] = {0, 0, 0, 0};
    float a3[4] = {0, 0, 0, 0}, a1[4] = {0, 0, 0, 0};
#pragma unroll
    for (int a = 0; a < 7; a++) {
        const float4* rp = (const float4*)&lx[(ty + a) * 40 + tx4];
        float4 v0 = rp[0], v1 = rp[1], v2 = rp[2];
        float v[12] = {v0.x, v0.y, v0.z, v0.w, v1.x, v1.y, v1.z, v1.w,
                       v2.x, v2.y, v2.z, v2.w};
#pragma unroll
        for (int j = 0; j < 4; j++) {
#pragma unroll
            for (int bb = 0; bb < 7; bb++)
                a7[j] = fmaf(v[j + bb], W7[a * 7 + bb], a7[j]);
            if (a >= 1 && a <= 5) {
#pragma unroll
                for (int bb = 0; bb < 5; bb++)
                    a5[j] = fmaf(v[j + 1 + bb], W5[(a - 1) * 5 + bb], a5[j]);
            }
            if (a >= 2 && a <= 4) {
#pragma unroll
                for (int bb = 0; bb < 3; bb++)
                    a3[j] = fmaf(v[j + 2 + bb], W3[(a - 2) * 3 + bb], a3[j]);
            }
            if (a == 3) a1[j] = v[j + 3] * W1;
        }
    }

    const int py = ty0 + ty, px = tx0 + tx4;
    const long row = (long)py * XS_STRIDE + 8 + px;
    float4 s1 = make_float4(a1[0] + B1, a1[1] + B1, a1[2] + B1, a1[3] + B1);
    float4 s3 = make_float4(a3[0] + B3, a3[1] + B3, a3[2] + B3, a3[3] + B3);
    float4 s5 = make_float4(a5[0] + B5, a5[1] + B5, a5[2] + B5, a5[3] + B5);
    float4 s7 = make_float4(a7[0] + B7, a7[1] + B7, a7[2] + B7, a7[3] + B7);
    *(float4*)&xs[(long)((bl * 4 + 0) * 16 + c) * XS_PLANE + row] = s1;
    *(float4*)&xs[(long)((bl * 4 + 1) * 16 + c) * XS_PLANE + row] = s3;
    *(float4*)&xs[(long)((bl * 4 + 2) * 16 + c) * XS_PLANE + row] = s5;
    *(float4*)&xs[(long)((bl * 4 + 3) * 16 + c) * XS_PLANE + row] = s7;

    // zero the pad columns (left 0..7, right 264..271) for all 4 branch planes
    float4 z = make_float4(0.f, 0.f, 0.f, 0.f);
    if (tx0 == 0 && tid < 64) {
        int r  = tid >> 1;
        int cc = (tid & 1) * 4;
        long rr = (long)(ty0 + r) * XS_STRIDE + cc;
#pragma unroll
        for (int i = 0; i < 4; i++)
            *(float4*)&xs[(long)((bl * 4 + i) * 16 + c) * XS_PLANE + rr] = z;
    }
    if (tx0 == 224 && tid < 64) {
        int r  = tid >> 1;
        int cc = 264 + (tid & 1) * 4;
        long rr = (long)(ty0 + r) * XS_STRIDE + cc;
#pragma unroll
        for (int i = 0; i < 4; i++)
            *(float4*)&xs[(long)((bl * 4 + i) * 16 + c) * XS_PLANE + rr] = z;
    }
}

// ---------------- K3: per-pixel machinery + fused final conv ----------------
#define CE(a, b) { float _lo = fminf(a, b); float _hi = fmaxf(a, b); a = _lo; b = _hi; }

__device__ __forceinline__ void sort8(float* v) {
    CE(v[0], v[1]); CE(v[2], v[3]); CE(v[4], v[5]); CE(v[6], v[7]);
    CE(v[0], v[2]); CE(v[1], v[3]); CE(v[4], v[6]); CE(v[5], v[7]);
    CE(v[1], v[2]); CE(v[5], v[6]); CE(v[0], v[4]); CE(v[3], v[7]);
    CE(v[1], v[5]); CE(v[2], v[6]);
    CE(v[1], v[4]); CE(v[3], v[6]);
    CE(v[2], v[4]); CE(v[3], v[5]);
    CE(v[3], v[4]);
}
__device__ __forceinline__ void sort4(float* v) {
    CE(v[0], v[1]); CE(v[2], v[3]); CE(v[0], v[2]); CE(v[1], v[3]); CE(v[1], v[2]);
}

__global__ __launch_bounds__(256, 4) void k_px(
    const float* __restrict__ xs,
    const float* __restrict__ l1w, const float* __restrict__ l1b,
    const float* __restrict__ l2w, const float* __restrict__ l2b,
    const float* __restrict__ bw,  const float* __restrict__ bns,
    const float* __restrict__ bnb, const float* __restrict__ fw,
    const float* __restrict__ fb,  float* __restrict__ out, int cb) {

    const int tid   = threadIdx.x;
    const int c     = tid >> 4;           // 0..15
    const int strip = tid & 15;           // 0..15
    const int x     = blockIdx.x * 64 + strip * 4;
    const int y     = blockIdx.y;
    const int bl    = blockIdx.z;         // 0..1
    const int b     = cb * 2 + bl;

    __shared__ float red[16][64];

    float br[4][4];                       // [px j][branch i]

#pragma unroll
    for (int i = 0; i < 4; i++) {
        const int s = 1 + 2 * i;          // 1,3,5,7
        const float* bp = xs + (long)((bl * 4 + i) * 16 + c) * XS_PLANE
                             + (long)y * XS_STRIDE + 8 + x;

        f4u ctr = *(const f4u*)bp;
        f4u m0  = *(const f4u*)(bp - s);        // (0,-s)
        f4u m1  = *(const f4u*)(bp + s);        // (0,+s)
        f4u a0 = {0, 0, 0, 0}, a1 = {0, 0, 0, 0}, a2 = {0, 0, 0, 0};
        f4u b0 = {0, 0, 0, 0}, b1 = {0, 0, 0, 0}, b2 = {0, 0, 0, 0};
        if (y >= s) {                           // block-uniform
            const float* tp = bp - s * XS_STRIDE;
            a0 = *(const f4u*)(tp - s); a1 = *(const f4u*)tp; a2 = *(const f4u*)(tp + s);
        }
        if (y + s < 256) {                      // block-uniform
            const float* bo = bp + s * XS_STRIDE;
            b0 = *(const f4u*)(bo - s); b1 = *(const f4u*)bo; b2 = *(const f4u*)(bo + s);
        }

        const float w10   = l1w[i * 64 + c * 4 + 0];
        const float w11   = l1w[i * 64 + c * 4 + 1];
        const float w12   = l1w[i * 64 + c * 4 + 2];
        const float w13x2 = 2.f * l1w[i * 64 + c * 4 + 3];
        const float bb1   = l1b[i * 16 + c];
        const float l2bv  = l2b[i * 16 + c];
        float l2wv[8];
#pragma unroll
        for (int k = 0; k < 8; k++) l2wv[k] = l2w[i * 128 + c * 8 + k];

#pragma unroll
        for (int j = 0; j < 4; j++) {
            const float cj = ctr[j];
            float T[8];
            T[0] = cj - a0[j]; T[1] = cj - a1[j]; T[2] = cj - a2[j];
            T[3] = cj - m1[j];
            T[4] = cj - b2[j]; T[5] = cj - b1[j]; T[6] = cj - b0[j];
            T[7] = cj - m0[j];
            float S[4];
#pragma unroll
            for (int k = 0; k < 4; k++) S[k] = T[k] + T[k + 4];

            float o8[8];
#pragma unroll
            for (int k = 0; k < 8; k++) {
                float o = fmaf(S[(k + 1) & 3], w10,
                          fmaf(S[(k + 3) & 3], w11,
                          fmaf(S[(k + 2) & 3], w12,
                          fmaf(T[(k + 4) & 7], w13x2, bb1))));
                o8[k] = o * T[k];
            }
            sort8(o8);
            float acc = l2bv;
#pragma unroll
            for (int k = 0; k < 8; k++) acc = fmaf(o8[k], l2wv[k], acc);
            br[j][i] = acc;
        }
    }

    const float bw0 = bw[c * 4 + 0], bw1 = bw[c * 4 + 1];
    const float bw2 = bw[c * 4 + 2], bw3 = bw[c * 4 + 3];
    const float bsc = bns[c], bbi = bnb[c], fwc = fw[c];

#pragma unroll
    for (int j = 0; j < 4; j++) {
        sort4(br[j]);
        float yv = br[j][0] * bw0;
        yv = fmaf(br[j][1], bw1, yv);
        yv = fmaf(br[j][2], bw2, yv);
        yv = fmaf(br[j][3], bw3, yv);
        float z   = fmaf(yv, bsc, bbi);
        float sil = z / (1.f + __expf(-z));
        red[c][strip * 4 + j] = sil * fwc;
    }
    __syncthreads();

    if (tid < 64) {
        float a = fb[0];
#pragma unroll
        for (int cc = 0; cc < 16; cc++) a += red[cc][tid];
        out[(long)b * HW + y * 256 + blockIdx.x * 64 + tid] = 1.f / (1.f + __expf(-a));
    }
}

extern "C" void kernel_launch(void* const* d_in, const int* in_sizes, int n_in,
                              void* d_out, int out_size, void* d_ws, size_t ws_size,
                              hipStream_t stream) {
    (void)in_sizes; (void)n_in; (void)out_size; (void)ws_size;
    const float* cen   = (const float*)d_in[0];
    // d_in[1] = mas (unused by the reference)
    const float* in_w  = (const float*)d_in[2];
    const float* in_b  = (const float*)d_in[3];
    const float* dw_w1 = (const float*)d_in[4];
    const float* dw_b1 = (const float*)d_in[5];
    const float* dw_w3 = (const float*)d_in[6];
    const float* dw_b3 = (const float*)d_in[7];
    const float* dw_w5 = (const float*)d_in[8];
    const float* dw_b5 = (const float*)d_in[9];
    const float* dw_w7 = (const float*)d_in[10];
    const float* dw_b7 = (const float*)d_in[11];
    const float* l1w   = (const float*)d_in[12];
    const float* l1b   = (const float*)d_in[13];
    const float* l2w   = (const float*)d_in[14];
    const float* l2b   = (const float*)d_in[15];
    const float* bw    = (const float*)d_in[16];
    const float* bns   = (const float*)d_in[17];
    const float* bnb   = (const float*)d_in[18];
    const float* fw    = (const float*)d_in[19];
    const float* fb    = (const float*)d_in[20];

    __half* xh = (__half*)d_ws;                           // (8,16,256,256) fp16, 16.78 MB
    float*  xs = (float*)((char*)d_ws + (size_t)8 * 16 * HW * 2);  // 2-batch padded chunk, 35.65 MB
    float*  out = (float*)d_out;

    k_inconv<<<512, 256, 0, stream>>>(cen, in_w, in_b, xh);
    for (int cb = 0; cb < 4; cb++) {
        k_dw<<<dim3(64, 32), 256, 0, stream>>>(xh, dw_w1, dw_b1, dw_w3, dw_b3,
                                               dw_w5, dw_b5, dw_w7, dw_b7, xs, cb);
        k_px<<<dim3(4, 256, 2), 256, 0, stream>>>(xs, l1w, l1b, l2w, l2b, bw,
                                                  bns, bnb, fw, fb, out, cb);
    }
}

// Round 4
// 418.143 us; speedup vs baseline: 1.5558x; 1.5558x over previous
//
#include <hip/hip_runtime.h>
#include <hip/hip_fp16.h>
#include <math.h>

#define HW 65536  // 256*256

// ---------------- K1: in_conv 1x1, 64 -> 16 ----------------
__global__ __launch_bounds__(256) void k_inconv(const float* __restrict__ cen,
                                                const float* __restrict__ w,
                                                const float* __restrict__ bias,
                                                float* __restrict__ x) {
    __shared__ float sw[1024];
    __shared__ float sb[16];
    int tid = threadIdx.x;
    for (int i = tid; i < 1024; i += 256) sw[i] = w[i];
    if (tid < 16) sb[tid] = bias[tid];
    __syncthreads();

    long t  = (long)blockIdx.x * 256 + tid;   // quad index
    long p0 = t * 4;
    int  b  = (int)(p0 >> 16);
    int  hw = (int)(p0 & 65535);

    const float4* src = (const float4*)(cen + ((long)b * 64) * HW + hw);
    float4 acc[16];
#pragma unroll
    for (int o = 0; o < 16; o++) { float bv = sb[o]; acc[o] = make_float4(bv, bv, bv, bv); }

    for (int i = 0; i < 64; i++) {
        float4 v = src[(long)i * (HW / 4)];
#pragma unroll
        for (int o = 0; o < 16; o++) {
            float wv = sw[o * 64 + i];
            acc[o].x = fmaf(v.x, wv, acc[o].x);
            acc[o].y = fmaf(v.y, wv, acc[o].y);
            acc[o].z = fmaf(v.z, wv, acc[o].z);
            acc[o].w = fmaf(v.w, wv, acc[o].w);
        }
    }
    float4* dst = (float4*)(x + ((long)b * 16) * HW + hw);
#pragma unroll
    for (int o = 0; o < 16; o++) dst[(long)o * (HW / 4)] = acc[o];
}

// ---------------- K2: fused branch machinery ----------------
#define CE(a, b) { float _lo = fminf(a, b); float _hi = fmaxf(a, b); a = _lo; b = _hi; }

__device__ __forceinline__ void sort8(float* v) {
    CE(v[0], v[1]); CE(v[2], v[3]); CE(v[4], v[5]); CE(v[6], v[7]);
    CE(v[0], v[2]); CE(v[1], v[3]); CE(v[4], v[6]); CE(v[5], v[7]);
    CE(v[1], v[2]); CE(v[5], v[6]); CE(v[0], v[4]); CE(v[3], v[7]);
    CE(v[1], v[5]); CE(v[2], v[6]);
    CE(v[1], v[4]); CE(v[3], v[6]);
    CE(v[2], v[4]); CE(v[3], v[5]);
    CE(v[3], v[4]);
}
__device__ __forceinline__ void sort4(float* v) {
    CE(v[0], v[1]); CE(v[2], v[3]); CE(v[0], v[2]); CE(v[1], v[3]); CE(v[1], v[2]);
}

#define LXS 56              // lx stride (52-wide tile, 16B-aligned rows)
#define SS  48              // lxs stride (46-wide, even -> b64, conflict-free)

__global__ __launch_bounds__(512, 6) void k_main(
    const float* __restrict__ x,
    const float* __restrict__ dw_w1, const float* __restrict__ dw_b1,
    const float* __restrict__ dw_w3, const float* __restrict__ dw_b3,
    const float* __restrict__ dw_w5, const float* __restrict__ dw_b5,
    const float* __restrict__ dw_w7, const float* __restrict__ dw_b7,
    const float* __restrict__ l1w, const float* __restrict__ l1b,
    const float* __restrict__ l2w, const float* __restrict__ l2b,
    const float* __restrict__ bw,  const float* __restrict__ bns,
    const float* __restrict__ bnb, __half* __restrict__ y16) {

    const int plane = blockIdx.y;          // b*16 + c
    const int c     = plane & 15;
    const int ty0   = (blockIdx.x >> 3) * 32;
    const int tx0   = (blockIdx.x & 7) * 32;
    const int tid   = threadIdx.x;

    __shared__ float lx[52 * LXS];         // x tile + halo 10
    __shared__ float lxs[4][46 * SS];      // dw outputs (zeroed outside image), halo 7

    const float* xp = x + (long)plane * HW;

    // ---- stage x tile (52x52, origin (ty0-10, tx0-10)), zero outside ----
    for (int i = tid; i < 52 * 52; i += 512) {
        int r  = i / 52;
        int cc = i - r * 52;
        int gy = ty0 - 10 + r, gx = tx0 - 10 + cc;
        float v = 0.f;
        if ((unsigned)gy < 256u && (unsigned)gx < 256u) v = xp[gy * 256 + gx];
        lx[r * LXS + cc] = v;
    }
    __syncthreads();

    // ---- depthwise convs into lxs over 46x46 (tile + halo 7), 2-px units ----
    const float* W7 = dw_w7 + c * 49;
    const float* W5 = dw_w5 + c * 25;
    const float* W3 = dw_w3 + c * 9;
    const float  W1 = dw_w1[c];
    const float  B1 = dw_b1[c], B3 = dw_b3[c], B5 = dw_b5[c], B7 = dw_b7[c];

    for (int u = tid; u < 46 * 23; u += 512) {   // 46 rows x 23 groups of 2 cols
        int row = u / 23;
        int pc0 = (u - row * 23) * 2;
        float c7[2] = {0, 0}, c5[2] = {0, 0}, c3[2] = {0, 0}, c1[2] = {0, 0};
#pragma unroll
        for (int a = 0; a < 7; a++) {
            const float2* rp = (const float2*)&lx[(row + a) * LXS + pc0];
            float2 p0 = rp[0], p1 = rp[1], p2 = rp[2], p3 = rp[3];
            float v[9] = {p0.x, p0.y, p1.x, p1.y, p2.x, p2.y, p3.x, p3.y,
                          lx[(row + a) * LXS + pc0 + 8]};
#pragma unroll
            for (int j = 0; j < 2; j++) {
#pragma unroll
                for (int bb = 0; bb < 7; bb++)
                    c7[j] = fmaf(v[j + bb], W7[a * 7 + bb], c7[j]);
                if (a >= 1 && a <= 5) {
#pragma unroll
                    for (int bb = 0; bb < 5; bb++)
                        c5[j] = fmaf(v[j + 1 + bb], W5[(a - 1) * 5 + bb], c5[j]);
                }
                if (a >= 2 && a <= 4) {
#pragma unroll
                    for (int bb = 0; bb < 3; bb++)
                        c3[j] = fmaf(v[j + 2 + bb], W3[(a - 2) * 3 + bb], c3[j]);
                }
                if (a == 3) c1[j] = v[j + 3] * W1;
            }
        }
        int gy  = ty0 - 7 + row;
        int gx0 = tx0 - 7 + pc0;
        bool rin = ((unsigned)gy < 256u);
        bool in0 = rin && ((unsigned)gx0 < 256u);
        bool in1 = rin && ((unsigned)(gx0 + 1) < 256u);
        int o = row * SS + pc0;
        float2 s;
        s.x = in0 ? c1[0] + B1 : 0.f; s.y = in1 ? c1[1] + B1 : 0.f;
        *(float2*)&lxs[0][o] = s;
        s.x = in0 ? c3[0] + B3 : 0.f; s.y = in1 ? c3[1] + B3 : 0.f;
        *(float2*)&lxs[1][o] = s;
        s.x = in0 ? c5[0] + B5 : 0.f; s.y = in1 ? c5[1] + B5 : 0.f;
        *(float2*)&lxs[2][o] = s;
        s.x = in0 ? c7[0] + B7 : 0.f; s.y = in1 ? c7[1] + B7 : 0.f;
        *(float2*)&lxs[3][o] = s;
    }
    __syncthreads();

    // ---- per-pixel branch machinery ----
    constexpr int OFFY[8] = {-1, -1, -1, 0, 1, 1, 1, 0};
    constexpr int OFFX[8] = {-1, 0, 1, 1, 1, 0, -1, -1};

    const float bsc = bns[c], bbi = bnb[c];
    const float bw0 = bw[c * 4 + 0], bw1 = bw[c * 4 + 1];
    const float bw2 = bw[c * 4 + 2], bw3 = bw[c * 4 + 3];

    for (int it = 0; it < 2; it++) {
        int p  = tid + it * 512;
        int ty = p >> 5, tx = p & 31;
        int gy = ty0 + ty, gx = tx0 + tx;
        const int corner = ty * SS + tx;   // lxs coords of (gy-7, gx-7)
        float br[4];
#pragma unroll
        for (int i = 0; i < 4; i++) {
            const int s = 1 + 2 * i;       // 1,3,5,7
            const float* xs = lxs[i];
            const float ctr = xs[corner + 7 * SS + 7];
            float T[8];
#pragma unroll
            for (int k = 0; k < 8; k++) {
                const int off = (7 + OFFY[k] * s) * SS + (7 + OFFX[k] * s);  // >=0, compile-time
                T[k] = ctr - xs[corner + off];
            }
            float S[4];
#pragma unroll
            for (int k = 0; k < 4; k++) S[k] = T[k] + T[k + 4];

            const float w10   = l1w[i * 64 + c * 4 + 0];
            const float w11   = l1w[i * 64 + c * 4 + 1];
            const float w12   = l1w[i * 64 + c * 4 + 2];
            const float w13x2 = 2.f * l1w[i * 64 + c * 4 + 3];
            const float bb1   = l1b[i * 16 + c];

            // R[m] = w10*S[(m+1)&3] + w11*S[(m+3)&3] + w12*S[(m+2)&3] + bb1
            float R[4];
#pragma unroll
            for (int m = 0; m < 4; m++)
                R[m] = fmaf(S[(m + 1) & 3], w10,
                       fmaf(S[(m + 3) & 3], w11,
                       fmaf(S[(m + 2) & 3], w12, bb1)));

            float o8[8];
#pragma unroll
            for (int k = 0; k < 8; k++)
                o8[k] = fmaf(T[(k + 4) & 7], w13x2, R[k & 3]) * T[k];
            sort8(o8);
            float acc = l2b[i * 16 + c];
#pragma unroll
            for (int k = 0; k < 8; k++) acc = fmaf(o8[k], l2w[i * 128 + c * 8 + k], acc);
            br[i] = acc;
        }
        sort4(br);
        float yv = br[0] * bw0;
        yv = fmaf(br[1], bw1, yv);
        yv = fmaf(br[2], bw2, yv);
        yv = fmaf(br[3], bw3, yv);
        float z   = fmaf(yv, bsc, bbi);
        float sil = z / (1.f + __expf(-z));          // z * sigmoid(z)
        y16[(long)plane * HW + gy * 256 + gx] = __float2half(sil);
    }
}

// ---------------- K3: final 1x1 16 -> 1 + sigmoid ----------------
__global__ __launch_bounds__(256) void k_final(const __half* __restrict__ y16,
                                               const float* __restrict__ fw,
                                               const float* __restrict__ fb,
                                               float* __restrict__ out) {
    long t  = (long)blockIdx.x * 256 + threadIdx.x;   // pair index
    long p0 = t * 2;
    int  b  = (int)(p0 >> 16);
    int  hw = (int)(p0 & 65535);

    float accx = fb[0], accy = fb[0];
#pragma unroll
    for (int cc = 0; cc < 16; cc++) {
        __half2 h = *(const __half2*)(y16 + (long)(b * 16 + cc) * HW + hw);
        float2 v = __half22float2(h);
        float wv = fw[cc];
        accx = fmaf(v.x, wv, accx);
        accy = fmaf(v.y, wv, accy);
    }
    float2 r;
    r.x = 1.f / (1.f + __expf(-accx));
    r.y = 1.f / (1.f + __expf(-accy));
    *(float2*)(out + p0) = r;
}

extern "C" void kernel_launch(void* const* d_in, const int* in_sizes, int n_in,
                              void* d_out, int out_size, void* d_ws, size_t ws_size,
                              hipStream_t stream) {
    (void)in_sizes; (void)n_in; (void)out_size; (void)ws_size;
    const float* cen   = (const float*)d_in[0];
    // d_in[1] = mas (unused by the reference)
    const float* in_w  = (const float*)d_in[2];
    const float* in_b  = (const float*)d_in[3];
    const float* dw_w1 = (const float*)d_in[4];
    const float* dw_b1 = (const float*)d_in[5];
    const float* dw_w3 = (const float*)d_in[6];
    const float* dw_b3 = (const float*)d_in[7];
    const float* dw_w5 = (const float*)d_in[8];
    const float* dw_b5 = (const float*)d_in[9];
    const float* dw_w7 = (const float*)d_in[10];
    const float* dw_b7 = (const float*)d_in[11];
    const float* l1w   = (const float*)d_in[12];
    const float* l1b   = (const float*)d_in[13];
    const float* l2w   = (const float*)d_in[14];
    const float* l2b   = (const float*)d_in[15];
    const float* bw    = (const float*)d_in[16];
    const float* bns   = (const float*)d_in[17];
    const float* bnb   = (const float*)d_in[18];
    const float* fw    = (const float*)d_in[19];
    const float* fb    = (const float*)d_in[20];

    float*  xbuf = (float*)d_ws;                           // (8,16,256,256) fp32, 33.5 MB
    __half* y16  = (__half*)(xbuf + (size_t)8 * 16 * HW);  // (8,16,256,256) fp16, 16.8 MB
    float*  out  = (float*)d_out;

    k_inconv<<<512, 256, 0, stream>>>(cen, in_w, in_b, xbuf);
    k_main<<<dim3(64, 128), 512, 0, stream>>>(xbuf, dw_w1, dw_b1, dw_w3, dw_b3,
                                              dw_w5, dw_b5, dw_w7, dw_b7,
                                              l1w, l1b, l2w, l2b, bw, bns, bnb, y16);
    k_final<<<1024, 256, 0, stream>>>(y16, fw, fb, out);
}

// Round 6
// 394.369 us; speedup vs baseline: 1.6496x; 1.0603x over previous
//
#include <hip/hip_runtime.h>
#include <hip/hip_fp16.h>
#include <math.h>

#define HW 65536  // 256*256

typedef float v2f __attribute__((ext_vector_type(2), aligned(4)));
typedef _Float16 h2 __attribute__((ext_vector_type(2)));

// ---------------- K1: in_conv 1x1, 64 -> 16 (1 px/thread) ----------------
__global__ __launch_bounds__(256, 8) void k_inconv(const float* __restrict__ cen,
                                                   const float* __restrict__ w,
                                                   const float* __restrict__ bias,
                                                   float* __restrict__ x) {
    int px = blockIdx.x * 256 + threadIdx.x;     // 0..524287  (b*HW + hw)
    int b  = px >> 16;
    int hw = px & 65535;

    const float* src = cen + (long)(b * 64) * HW + hw;
    float acc[16];
#pragma unroll
    for (int o = 0; o < 16; o++) acc[o] = bias[o];

#pragma unroll 4
    for (int i = 0; i < 64; i++) {
        float v = src[(long)i * HW];
#pragma unroll
        for (int o = 0; o < 16; o++) acc[o] = fmaf(v, w[o * 64 + i], acc[o]);
    }
    float* dst = x + (long)(b * 16) * HW + hw;
#pragma unroll
    for (int o = 0; o < 16; o++) dst[(long)o * HW] = acc[o];
}

// ---------------- K2: fused branch machinery (2-px packed) ----------------
// fp32 packed compare-exchange not available -> fp16 packed sort (v_pk_min/max_f16)
#define CEH(a, b) { h2 _t = __builtin_elementwise_min(a, b); \
                    b = __builtin_elementwise_max(a, b); a = _t; }

__device__ __forceinline__ void sort8_h2(h2* v) {
    CEH(v[0], v[1]); CEH(v[2], v[3]); CEH(v[4], v[5]); CEH(v[6], v[7]);
    CEH(v[0], v[2]); CEH(v[1], v[3]); CEH(v[4], v[6]); CEH(v[5], v[7]);
    CEH(v[1], v[2]); CEH(v[5], v[6]); CEH(v[0], v[4]); CEH(v[3], v[7]);
    CEH(v[1], v[5]); CEH(v[2], v[6]);
    CEH(v[1], v[4]); CEH(v[3], v[6]);
    CEH(v[2], v[4]); CEH(v[3], v[5]);
    CEH(v[3], v[4]);
}
__device__ __forceinline__ void sort4_h2(h2* v) {
    CEH(v[0], v[1]); CEH(v[2], v[3]); CEH(v[0], v[2]); CEH(v[1], v[3]); CEH(v[1], v[2]);
}

#define LXS 56              // lx stride (52-wide tile, 16B-aligned rows)
#define SS  48              // lxs stride (46-wide, even)

__global__ __launch_bounds__(512, 4) void k_main(
    const float* __restrict__ x,
    const float* __restrict__ dw_w1, const float* __restrict__ dw_b1,
    const float* __restrict__ dw_w3, const float* __restrict__ dw_b3,
    const float* __restrict__ dw_w5, const float* __restrict__ dw_b5,
    const float* __restrict__ dw_w7, const float* __restrict__ dw_b7,
    const float* __restrict__ l1w, const float* __restrict__ l1b,
    const float* __restrict__ l2w, const float* __restrict__ l2b,
    const float* __restrict__ bw,  const float* __restrict__ bns,
    const float* __restrict__ bnb, __half* __restrict__ y16) {

    const int plane = blockIdx.y;          // b*16 + c
    const int c     = plane & 15;
    const int ty0   = (blockIdx.x >> 3) * 32;
    const int tx0   = (blockIdx.x & 7) * 32;
    const int tid   = threadIdx.x;

    __shared__ float lx[52 * LXS];         // x tile + halo 10
    __shared__ float lxs[4][46 * SS];      // dw outputs (zeroed outside image), halo 7

    const float* xp = x + (long)plane * HW;

    // ---- stage x tile (52x52, origin (ty0-10, tx0-10)), zero outside ----
    for (int i = tid; i < 52 * 52; i += 512) {
        int r  = i / 52;
        int cc = i - r * 52;
        int gy = ty0 - 10 + r, gx = tx0 - 10 + cc;
        float v = 0.f;
        if ((unsigned)gy < 256u && (unsigned)gx < 256u) v = xp[gy * 256 + gx];
        lx[r * LXS + cc] = v;
    }
    __syncthreads();

    // ---- depthwise convs into lxs over 46x46 (tile + halo 7), 2-px packed ----
    const float* W7 = dw_w7 + c * 49;
    const float* W5 = dw_w5 + c * 25;
    const float* W3 = dw_w3 + c * 9;
    const float  W1 = dw_w1[c];
    const float  B1 = dw_b1[c], B3 = dw_b3[c], B5 = dw_b5[c], B7 = dw_b7[c];

    for (int u = tid; u < 46 * 23; u += 512) {   // 46 rows x 23 groups of 2 cols
        int row = u / 23;
        int pc0 = (u - row * 23) * 2;
        v2f c7 = {0, 0}, c5 = {0, 0}, c3 = {0, 0}, c1 = {0, 0};
#pragma unroll
        for (int a = 0; a < 7; a++) {
            const float* rp = &lx[(row + a) * LXS + pc0];
            v2f q0 = *(const v2f*)rp;
            v2f q1 = *(const v2f*)(rp + 2);
            v2f q2 = *(const v2f*)(rp + 4);
            v2f q3 = *(const v2f*)(rp + 6);
            float v8 = rp[8];
            float v[9] = {q0.x, q0.y, q1.x, q1.y, q2.x, q2.y, q3.x, q3.y, v8};
#pragma unroll
            for (int bb = 0; bb < 7; bb++) {
                v2f vv = {v[bb], v[bb + 1]};
                c7 += vv * W7[a * 7 + bb];      // v_pk_fma_f32
            }
            if (a >= 1 && a <= 5) {
#pragma unroll
                for (int bb = 0; bb < 5; bb++) {
                    v2f vv = {v[bb + 1], v[bb + 2]};
                    c5 += vv * W5[(a - 1) * 5 + bb];
                }
            }
            if (a >= 2 && a <= 4) {
#pragma unroll
                for (int bb = 0; bb < 3; bb++) {
                    v2f vv = {v[bb + 2], v[bb + 3]};
                    c3 += vv * W3[(a - 2) * 3 + bb];
                }
            }
            if (a == 3) {
                v2f vv = {v[3], v[4]};
                c1 = vv * W1;
            }
        }
        int gy  = ty0 - 7 + row;
        int gx0 = tx0 - 7 + pc0;
        bool rin = ((unsigned)gy < 256u);
        bool in0 = rin && ((unsigned)gx0 < 256u);
        bool in1 = rin && ((unsigned)(gx0 + 1) < 256u);
        int o = row * SS + pc0;
        v2f s;
        s.x = in0 ? c1.x + B1 : 0.f; s.y = in1 ? c1.y + B1 : 0.f;
        *(v2f*)&lxs[0][o] = s;
        s.x = in0 ? c3.x + B3 : 0.f; s.y = in1 ? c3.y + B3 : 0.f;
        *(v2f*)&lxs[1][o] = s;
        s.x = in0 ? c5.x + B5 : 0.f; s.y = in1 ? c5.y + B5 : 0.f;
        *(v2f*)&lxs[2][o] = s;
        s.x = in0 ? c7.x + B7 : 0.f; s.y = in1 ? c7.y + B7 : 0.f;
        *(v2f*)&lxs[3][o] = s;
    }
    __syncthreads();

    // ---- per-pixel machinery: one horizontal pixel PAIR per thread ----
    const int ty  = tid >> 4;           // 0..31
    const int tx2 = (tid & 15) * 2;     // 0,2,...,30
    const int gy  = ty0 + ty, gx = tx0 + tx2;
    const int corner = ty * SS + tx2;   // lxs coords of (gy-7, gx-7)

    v2f br[4];
#pragma unroll
    for (int i = 0; i < 4; i++) {
        const int s = 1 + 2 * i;        // 1,3,5,7
        const float* xs = lxs[i];
        v2f ctr = *(const v2f*)&xs[corner + 7 * SS + 7];
        v2f n0  = *(const v2f*)&xs[corner + (7 - s) * SS + (7 - s)];
        v2f n1  = *(const v2f*)&xs[corner + (7 - s) * SS + 7];
        v2f n2  = *(const v2f*)&xs[corner + (7 - s) * SS + (7 + s)];
        v2f n3  = *(const v2f*)&xs[corner + 7 * SS + (7 + s)];
        v2f n4  = *(const v2f*)&xs[corner + (7 + s) * SS + (7 + s)];
        v2f n5  = *(const v2f*)&xs[corner + (7 + s) * SS + 7];
        v2f n6  = *(const v2f*)&xs[corner + (7 + s) * SS + (7 - s)];
        v2f n7  = *(const v2f*)&xs[corner + 7 * SS + (7 - s)];

        v2f T[8];
        T[0] = ctr - n0; T[1] = ctr - n1; T[2] = ctr - n2; T[3] = ctr - n3;
        T[4] = ctr - n4; T[5] = ctr - n5; T[6] = ctr - n6; T[7] = ctr - n7;
        v2f S[4];
#pragma unroll
        for (int k = 0; k < 4; k++) S[k] = T[k] + T[k + 4];

        const float w10   = l1w[i * 64 + c * 4 + 0];
        const float w11   = l1w[i * 64 + c * 4 + 1];
        const float w12   = l1w[i * 64 + c * 4 + 2];
        const float w13x2 = 2.f * l1w[i * 64 + c * 4 + 3];
        const float bb1   = l1b[i * 16 + c];

        v2f R[4];
#pragma unroll
        for (int m = 0; m < 4; m++) {
            v2f r = S[(m + 2) & 3] * w12 + bb1;
            r = S[(m + 3) & 3] * w11 + r;
            r = S[(m + 1) & 3] * w10 + r;
            R[m] = r;
        }

        h2 h8[8];
#pragma unroll
        for (int k = 0; k < 8; k++) {
            v2f o = (T[(k + 4) & 7] * w13x2 + R[k & 3]) * T[k];
            h8[k] = __builtin_convertvector(o, h2);
        }
        sort8_h2(h8);

        v2f acc = {l2b[i * 16 + c], l2b[i * 16 + c]};
#pragma unroll
        for (int k = 0; k < 8; k++) {
            v2f ov = __builtin_convertvector(h8[k], v2f);
            acc += ov * l2w[i * 128 + c * 8 + k];
        }
        br[i] = acc;
    }

    // sort over branches (fp16 packed), then base_w dot in fp32
    h2 bh[4];
#pragma unroll
    for (int i = 0; i < 4; i++) bh[i] = __builtin_convertvector(br[i], h2);
    sort4_h2(bh);

    v2f yv = {0.f, 0.f};
#pragma unroll
    for (int i = 0; i < 4; i++) {
        v2f bv = __builtin_convertvector(bh[i], v2f);
        yv += bv * bw[c * 4 + i];
    }
    const float bsc = bns[c], bbi = bnb[c];
    float zx = fmaf(yv.x, bsc, bbi);
    float zy = fmaf(yv.y, bsc, bbi);
    float sx = zx / (1.f + __expf(-zx));
    float sy = zy / (1.f + __expf(-zy));
    *(__half2*)&y16[(long)plane * HW + gy * 256 + gx] = __floats2half2_rn(sx, sy);
}

// ---------------- K3: final 1x1 16 -> 1 + sigmoid ----------------
__global__ __launch_bounds__(256) void k_final(const __half* __restrict__ y16,
                                               const float* __restrict__ fw,
                                               const float* __restrict__ fb,
                                               float* __restrict__ out) {
    long t  = (long)blockIdx.x * 256 + threadIdx.x;   // pair index
    long p0 = t * 2;
    int  b  = (int)(p0 >> 16);
    int  hw = (int)(p0 & 65535);

    float accx = fb[0], accy = fb[0];
#pragma unroll
    for (int cc = 0; cc < 16; cc++) {
        __half2 h = *(const __half2*)(y16 + (long)(b * 16 + cc) * HW + hw);
        float2 v = __half22float2(h);
        float wv = fw[cc];
        accx = fmaf(v.x, wv, accx);
        accy = fmaf(v.y, wv, accy);
    }
    float2 r;
    r.x = 1.f / (1.f + __expf(-accx));
    r.y = 1.f / (1.f + __expf(-accy));
    *(float2*)(out + p0) = r;
}

extern "C" void kernel_launch(void* const* d_in, const int* in_sizes, int n_in,
                              void* d_out, int out_size, void* d_ws, size_t ws_size,
                              hipStream_t stream) {
    (void)in_sizes; (void)n_in; (void)out_size; (void)ws_size;
    const float* cen   = (const float*)d_in[0];
    // d_in[1] = mas (unused by the reference)
    const float* in_w  = (const float*)d_in[2];
    const float* in_b  = (const float*)d_in[3];
    const float* dw_w1 = (const float*)d_in[4];
    const float* dw_b1 = (const float*)d_in[5];
    const float* dw_w3 = (const float*)d_in[6];
    const float* dw_b3 = (const float*)d_in[7];
    const float* dw_w5 = (const float*)d_in[8];
    const float* dw_b5 = (const float*)d_in[9];
    const float* dw_w7 = (const float*)d_in[10];
    const float* dw_b7 = (const float*)d_in[11];
    const float* l1w   = (const float*)d_in[12];
    const float* l1b   = (const float*)d_in[13];
    const float* l2w   = (const float*)d_in[14];
    const float* l2b   = (const float*)d_in[15];
    const float* bw    = (const float*)d_in[16];
    const float* bns   = (const float*)d_in[17];
    const float* bnb   = (const float*)d_in[18];
    const float* fw    = (const float*)d_in[19];
    const float* fb    = (const float*)d_in[20];

    float*  xbuf = (float*)d_ws;                           // (8,16,256,256) fp32, 33.5 MB
    __half* y16  = (__half*)(xbuf + (size_t)8 * 16 * HW);  // (8,16,256,256) fp16, 16.8 MB
    float*  out  = (float*)d_out;

    k_inconv<<<2048, 256, 0, stream>>>(cen, in_w, in_b, xbuf);
    k_main<<<dim3(64, 128), 512, 0, stream>>>(xbuf, dw_w1, dw_b1, dw_w3, dw_b3,
                                              dw_w5, dw_b5, dw_w7, dw_b7,
                                              l1w, l1b, l2w, l2b, bw, bns, bnb, y16);
    k_final<<<1024, 256, 0, stream>>>(y16, fw, fb, out);
}